// Round 2
// baseline (345.136 us; speedup 1.0000x reference)
//
#include <hip/hip_runtime.h>
#include <math.h>

// Word_Graph_Attention: out[b,s,:] = softmax_n(leaky(cos(Qn, Kn))) @ K
//   K = v @ V_w^T + V_b   (8.19-GFLOP core as bf16 MFMA 16x16x32)
// Inputs fp32: 0=input_ent(unused) 1=q 2=k(unused) 3=v 4=Q_w 5=Q_b 6=V_w 7=V_b
// Output fp32 [32,256,100]
//
// R2 changes: (1) NO d_ws use — round-1 wrote 12.8KB of Qn into d_ws without
// checking ws_size; theory: overflow corrupted the harness's pristine input
// copies -> deterministic post-timing divergence. Qn now recomputed per block.
// (2) all conditionally-written LDS zero-initialized once (no NaN channels).
// (3) coalesced float4 v staging + software-pipelined prefetch; Kl padded.

#define S_DIM 256
#define N_NBR 50
#define D_F   100
#define QD    768
#define NT    7      // 7 x 16 = 112 >= 100 output-feature tiles
#define KC    4      // 4 x 32 = 128 >= 100 contraction chunks
#define TILE_F4 1250 // 50*100/4 float4 per (b,s) tile
#define ITERS 16

typedef __attribute__((ext_vector_type(4))) float f32x4;
typedef __attribute__((ext_vector_type(8))) short s16x8;
typedef __attribute__((ext_vector_type(4))) short s16x4;

__device__ __forceinline__ short f2bf(float f) {
  union { float f; unsigned u; } x; x.f = f;
  unsigned r = x.u + 0x7fffu + ((x.u >> 16) & 1u);   // RNE
  return (short)(r >> 16);
}

__global__ __launch_bounds__(256, 2) void wga_kernel(
    const float* __restrict__ v, const float* __restrict__ q,
    const float* __restrict__ Qw, const float* __restrict__ Qb,
    const float* __restrict__ Vw, const float* __restrict__ Vb,
    float* __restrict__ out) {
  __shared__ __align__(16) short Abuf[KC * 4 * 64 * 8];   // 16 KB, fragment order
  __shared__ float Kl[N_NBR + 2][105];                    // padded stride
  __shared__ __align__(16) float attS[64];
  __shared__ float QnS[112];
  __shared__ float nrm2[64], srw[64];
  __shared__ float qs[QD];
  __shared__ float Qpart[256];
  __shared__ float rnS;

  const int t  = threadIdx.x;
  const int w  = t >> 6, l = t & 63;
  const int qd = l >> 4, m = l & 15;
  const int blk = blockIdx.x;
  const int b   = blk >> 4;
  const int s0  = (blk & 15) * ITERS;

  // ---- prefetch tile it=0 (coalesced float4) ----
  f32x4 pf[5];
  {
    const f32x4* vt = (const f32x4*)(v + (size_t)(b * S_DIM + s0) * (N_NBR * D_F));
#pragma unroll
    for (int j = 0; j < 5; ++j) {
      const int i = t + 256 * j;
      if (i < TILE_F4) pf[j] = vt[i];
    }
  }

  // ---- per-block constants: B fragments (W^T bf16, zero-padded) + bias ----
  s16x8 bfrag[NT][KC];
  float bias[NT], QnSv[NT];
#pragma unroll
  for (int nt = 0; nt < NT; ++nt) {
    const int e = nt * 16 + m;
    bias[nt] = (e < D_F) ? Vb[e] : 0.f;
#pragma unroll
    for (int c = 0; c < KC; ++c) {
      const int k0 = c * 32 + qd * 8;
      s16x8 pk;
#pragma unroll
      for (int j = 0; j < 8; ++j) {
        const int k = k0 + j;
        const float x = (e < D_F && k < D_F) ? Vw[e * D_F + k] : 0.f;
        pk[j] = f2bf(x);
      }
      bfrag[nt][c] = pk;
    }
  }

  // ---- zero-init LDS edges (once) + stage q ----
  {
    int4* az = (int4*)Abuf;
    for (int i = t; i < 1024; i += 256) az[i] = make_int4(0, 0, 0, 0);  // 16 KB
    float* klz = &Kl[N_NBR][0];
    if (t < 210) klz[t] = 0.f;                                         // rows 50,51
    for (int i = t; i < QD; i += 256) qs[i] = q[b * QD + i];
  }
  __syncthreads();

  // ---- Qn = normalize(q[b] @ Qw^T + Qb), fused per block (no d_ws!) ----
  if (t < 200) {
    const int e = t >> 1, h = t & 1;
    const float4* wr = (const float4*)(Qw + e * QD + h * 384);
    const float4* qv = (const float4*)(qs + h * 384);
    float a0 = 0.f, a1 = 0.f, a2 = 0.f, a3 = 0.f;
#pragma unroll 4
    for (int f = 0; f < 96; ++f) {
      float4 wv = wr[f], qf = qv[f];
      a0 += wv.x * qf.x; a1 += wv.y * qf.y; a2 += wv.z * qf.z; a3 += wv.w * qf.w;
    }
    Qpart[t] = (a0 + a1) + (a2 + a3);
  }
  __syncthreads();
  if (t < D_F)       QnS[t] = Qpart[2 * t] + Qpart[2 * t + 1] + Qb[t];
  else if (t < 112)  QnS[t] = 0.f;
  __syncthreads();
  if (w == 0) {
    float x = QnS[l] * QnS[l];
    if (l < 48) x += QnS[64 + l] * QnS[64 + l];   // QnS[100..111]==0
#pragma unroll
    for (int d = 1; d < 64; d <<= 1) x += __shfl_xor(x, d, 64);
    if (l == 0) rnS = 1.0f / fmaxf(sqrtf(x), 1e-12f);
  }
  __syncthreads();
  if (t < D_F) QnS[t] *= rnS;
  __syncthreads();
#pragma unroll
  for (int nt = 0; nt < NT; ++nt) QnSv[nt] = QnS[nt * 16 + m];

  for (int it = 0; it < ITERS; ++it) {
    // ---- write prefetched tile -> Abuf in MFMA fragment order (bf16) ----
#pragma unroll
    for (int j = 0; j < 5; ++j) {
      const int i = t + 256 * j;
      if (i < TILE_F4) {
        const int n  = i / 25;            // row 0..49
        const int k4 = (i - n * 25) * 4;  // k 0..96 step 4
        const int wv = n >> 4, mm = n & 15;
        const int c = k4 >> 5, qq = (k4 >> 3) & 3, j0 = k4 & 7;
        s16x4 p;
        p[0] = f2bf(pf[j][0]); p[1] = f2bf(pf[j][1]);
        p[2] = f2bf(pf[j][2]); p[3] = f2bf(pf[j][3]);
        *(s16x4*)&Abuf[(((c * 4 + wv) * 64 + qq * 16 + mm) << 3) + j0] = p;
      }
    }
    __syncthreads();   // barrier1: Abuf ready

    // ---- prefetch next tile (latency hidden under MFMA/softmax/epilogue) ----
    if (it + 1 < ITERS) {
      const f32x4* vt = (const f32x4*)(v + (size_t)(b * S_DIM + s0 + it + 1) * (N_NBR * D_F));
#pragma unroll
      for (int j = 0; j < 5; ++j) {
        const int i = t + 256 * j;
        if (i < TILE_F4) pf[j] = vt[i];
      }
    }

    // ---- MFMA: wave w computes K rows 16w..16w+15 ----
    f32x4 acc[NT];
#pragma unroll
    for (int nt = 0; nt < NT; ++nt) {
      f32x4 z; z[0] = bias[nt]; z[1] = bias[nt]; z[2] = bias[nt]; z[3] = bias[nt];
      acc[nt] = z;
    }
    s16x8 af[KC];
#pragma unroll
    for (int c = 0; c < KC; ++c)
      af[c] = *(const s16x8*)&Abuf[((c * 4 + w) * 64 + l) * 8];
#pragma unroll
    for (int c = 0; c < KC; ++c)
#pragma unroll
      for (int nt = 0; nt < NT; ++nt)
        acc[nt] = __builtin_amdgcn_mfma_f32_16x16x32_bf16(af[c], bfrag[nt][c], acc[nt], 0, 0, 0);

    // ---- row |K|^2 and Qn.K (reduce across 16 col-lanes) ----
#pragma unroll
    for (int r = 0; r < 4; ++r) {
      float np = 0.f, sp = 0.f;
#pragma unroll
      for (int nt = 0; nt < NT; ++nt) {
        const float kv = acc[nt][r];       // row = 16w+4qd+r, col = 16nt+m
        np += kv * kv;
        sp += QnSv[nt] * kv;
      }
#pragma unroll
      for (int d = 1; d < 16; d <<= 1) {
        np += __shfl_xor(np, d, 64);
        sp += __shfl_xor(sp, d, 64);
      }
      if (m == 0) {
        const int row = w * 16 + qd * 4 + r;
        nrm2[row] = np; srw[row] = sp;
      }
    }
    // ---- spill K for epilogue ----
#pragma unroll
    for (int nt = 0; nt < NT; ++nt) {
      const int col = nt * 16 + m;
#pragma unroll
      for (int r = 0; r < 4; ++r) {
        const int row = w * 16 + qd * 4 + r;
        if (row < N_NBR && col < D_F) Kl[row][col] = acc[nt][r];
      }
    }
    __syncthreads();   // barrier2

    // ---- softmax over 50 neighbors (wave 0), exact reference semantics ----
    if (w == 0) {
      float a = -1e30f;
      if (l < N_NBR) {
        float l2 = sqrtf(nrm2[l]);
        if (l2 == 0.f) l2 = 1e-6f;          // where(l2==0, 1e-6)
        float sc = srw[l] / l2;             // cosine similarity
        if (sc == 0.f) sc = -10000.f;       // where(att==0, -10000)
        a = (sc >= 0.f) ? sc : 0.01f * sc;  // leaky_relu 0.01
      }
      float mx = a;
#pragma unroll
      for (int d = 1; d < 64; d <<= 1) mx = fmaxf(mx, __shfl_xor(mx, d, 64));
      const float e = (l < N_NBR) ? __expf(a - mx) : 0.f;
      float sm = e;
#pragma unroll
      for (int d = 1; d < 64; d <<= 1) sm += __shfl_xor(sm, d, 64);
      float att = e / sm;
      if (att == 0.02f) att = 0.f;          // where(att == 1/50, 0)
      attS[l] = (l < N_NBR) ? att : 0.f;
    }
    __syncthreads();   // barrier3

    // ---- out[e] = sum_n att[n] * K[n][e] ----
    if (t < D_F) {
      float o = 0.f;
#pragma unroll
      for (int c = 0; c < 13; ++c) {        // 52 rows; 50,51 are zeroed LDS x att=0
        float4 av = *(const float4*)&attS[c * 4];
        o += av.x * Kl[c * 4 + 0][t];
        o += av.y * Kl[c * 4 + 1][t];
        o += av.z * Kl[c * 4 + 2][t];
        o += av.w * Kl[c * 4 + 3][t];
      }
      out[(size_t)(b * S_DIM + s0 + it) * D_F + t] = o;
    }
  }
}

extern "C" void kernel_launch(void* const* d_in, const int* in_sizes, int n_in,
                              void* d_out, int out_size, void* d_ws, size_t ws_size,
                              hipStream_t stream) {
  const float* q  = (const float*)d_in[1];
  const float* v  = (const float*)d_in[3];
  const float* Qw = (const float*)d_in[4];
  const float* Qb = (const float*)d_in[5];
  const float* Vw = (const float*)d_in[6];
  const float* Vb = (const float*)d_in[7];
  float* out = (float*)d_out;
  (void)d_ws; (void)ws_size;   // deliberately unused — see header comment

  wga_kernel<<<512, 256, 0, stream>>>(v, q, Qw, Qb, Vw, Vb, out);
}